// Round 1
// baseline (912.970 us; speedup 1.0000x reference)
//
#include <hip/hip_runtime.h>

// CRF log-likelihood: B=256, S=2048, L=64, START=62, END=63.
// One wave (64 lanes) per batch element; lane i owns state i.
// Forward recurrence in base-2 log domain with probability-domain matvec:
//   P[i][j] = exp(T[i,j]) held in 64 VGPRs per lane (precomputed once).
//   Per step: E = 2^alpha_rel (1 exp), s_i = sum_j P[i][j]*readlane(E,j),
//   alpha' = log2(s_i) + logit*log2e, renorm by lane-0 value (no butterfly).

#define Bsz 256
#define Ssz 2048
#define Lsz 64
#define START_ 62
#define END_ 63

__device__ __forceinline__ float rdlane(float v, int l) {
    return __int_as_float(__builtin_amdgcn_readlane(__float_as_int(v), l));
}

__device__ __forceinline__ float wave_sum(float v) {
#pragma unroll
    for (int m = 32; m >= 1; m >>= 1)
        v += __shfl_xor(v, m, 64);
    return v;
}

__global__ __launch_bounds__(64, 1)
void crf_kernel(const float* __restrict__ logits,
                const float* __restrict__ transition,
                const int* __restrict__ labels,
                const int* __restrict__ lens,
                float* __restrict__ out) {
    const int b = blockIdx.x;
    const int lane = threadIdx.x;
    const int len = lens[b];                 // 1..2048, uniform per wave
    const float LOG2E = 1.4426950408889634f;
    const float LN2   = 0.69314718055994531f;

    // P[j] = exp(T[lane][j]); forbidden (-100) entries underflow to 0.
    float P[64];
#pragma unroll
    for (int j = 0; j < 64; ++j)
        P[j] = __builtin_amdgcn_exp2f(transition[lane * 64 + j] * LOG2E);

    const float* lrow = logits + (size_t)b * Ssz * Lsz;

    // alpha in base-2, renormalized; true alpha2 = a + C.
    float a = (lane == START_) ? 0.0f : -100.0f * LOG2E;
    float C = 0.0f;

    // Rolling 4-deep logits prefetch (coalesced 256B/row).
    float lgbuf[4];
#pragma unroll
    for (int d = 0; d < 4; ++d) {
        int s = (d < len) ? d : (len - 1);
        lgbuf[d] = lrow[s * 64 + lane];
    }

    for (int base = 0; base < len; base += 4) {
#pragma unroll
        for (int d = 0; d < 4; ++d) {
            int s = base + d;
            if (s < len) {
                float lg = lgbuf[d];
                int pf = base + 4 + d;
                if (pf >= len) pf = len - 1;
                lgbuf[d] = lrow[pf * 64 + lane];     // prefetch 4 ahead

                float E = __builtin_amdgcn_exp2f(a); // one exp per step
                float acc0 = 0.f, acc1 = 0.f, acc2 = 0.f, acc3 = 0.f;
#pragma unroll
                for (int j = 0; j < 64; j += 4) {
                    acc0 = __builtin_fmaf(P[j + 0], rdlane(E, j + 0), acc0);
                    acc1 = __builtin_fmaf(P[j + 1], rdlane(E, j + 1), acc1);
                    acc2 = __builtin_fmaf(P[j + 2], rdlane(E, j + 2), acc2);
                    acc3 = __builtin_fmaf(P[j + 3], rdlane(E, j + 3), acc3);
                }
                float ssum = (acc0 + acc1) + (acc2 + acc3);
                float anew = __builtin_fmaf(lg, LOG2E,
                                            __builtin_amdgcn_logf(ssum));
                float a0 = rdlane(anew, 0);          // lane-0 renorm
                a = anew - a0;
                C += a0;
            }
        }
    }

    // norm = ln2 * (C + log2( sum_i 2^a_i * exp(T[END,i]) ))
    float Pend = __builtin_amdgcn_exp2f(transition[END_ * 64 + lane] * LOG2E);
    float t = __builtin_amdgcn_exp2f(a) * Pend;
    float tot = wave_sum(t);
    float norm = LN2 * (C + __builtin_amdgcn_logf(tot));

    // Gold path score: parallel gather over s, wave-reduce.
    const int* lab = labels + (size_t)b * Ssz;
    float g = 0.0f;
    for (int s = lane; s < len; s += 64) {
        int l1 = lab[s];
        int l0 = (s == 0) ? START_ : lab[s - 1];
        g += lrow[s * 64 + l1] + transition[l1 * 64 + l0];
    }
    if (lane == 0) g += transition[END_ * 64 + lab[len - 1]];
    float gold = wave_sum(g);

    if (lane == 0) out[b] = gold - norm;
}

extern "C" void kernel_launch(void* const* d_in, const int* in_sizes, int n_in,
                              void* d_out, int out_size, void* d_ws, size_t ws_size,
                              hipStream_t stream) {
    const float* logits     = (const float*)d_in[0];
    const float* transition = (const float*)d_in[1];
    const int*   labels     = (const int*)d_in[2];
    const int*   lens       = (const int*)d_in[3];
    float*       out        = (float*)d_out;

    crf_kernel<<<dim3(Bsz), dim3(64), 0, stream>>>(
        logits, transition, labels, lens, out);
}